// Round 1
// baseline (138.230 us; speedup 1.0000x reference)
//
#include <hip/hip_runtime.h>
#include <cstdint>

#define LL 1024   // sequence length L
#define DD 1024   // dim D
#define NB 16     // batch
#define NHH 8     // heads

typedef __bf16 bf16x8 __attribute__((ext_vector_type(8)));
typedef float f32x4 __attribute__((ext_vector_type(4)));

#define GPTR(x) ((const __attribute__((address_space(1))) void*)(x))
#define LPTR(x) ((__attribute__((address_space(3))) void*)(x))

static __device__ __forceinline__ unsigned short f2b(float f) {
  unsigned int u = __float_as_uint(f);
  u += 0x7FFFu + ((u >> 16) & 1u);
  return (unsigned short)(u >> 16);
}

// ---------------------------------------------------------------------------
// Kernel 1: w_eff[o,m] = sum_h out_w[o, h*D + m]  (store bf16), S[o] = sum_m w_eff
// ---------------------------------------------------------------------------
__global__ __launch_bounds__(256) void weff_kernel(const float* __restrict__ out_w,
                                                   unsigned short* __restrict__ weff,
                                                   float* __restrict__ S) {
  const int o = blockIdx.x;
  const int t = threadIdx.x;
  __shared__ float red[256];
  const float* row = out_w + (size_t)o * (DD * NHH);
  float local = 0.f;
#pragma unroll
  for (int i = 0; i < 4; ++i) {
    int m = t + i * 256;
    float s = 0.f;
#pragma unroll
    for (int h = 0; h < NHH; ++h) s += row[h * DD + m];
    weff[(size_t)o * DD + m] = f2b(s);
    local += s;
  }
  red[t] = local;
  __syncthreads();
  for (int st = 128; st > 0; st >>= 1) {
    if (t < st) red[t] += red[t + st];
    __syncthreads();
  }
  if (t == 0) S[o] = red[0];
}

// ---------------------------------------------------------------------------
// Kernel 2: W = softmax(tril(conv_w)) rows; upper triangle contributes exp(0)=1.
// Store bf16.
// ---------------------------------------------------------------------------
__global__ __launch_bounds__(256) void softmax_kernel(const float* __restrict__ conv_w,
                                                      unsigned short* __restrict__ Wb) {
  const int f = blockIdx.x;
  const int t = threadIdx.x;
  __shared__ float red[256];
  float z[4];
  float mx = -1e30f;
#pragma unroll
  for (int i = 0; i < 4; ++i) {
    int d = t + i * 256;
    float v = conv_w[(size_t)f * LL + d];
    z[i] = (d <= f) ? v : 0.f;
    mx = fmaxf(mx, z[i]);
  }
  red[t] = mx;
  __syncthreads();
  for (int st = 128; st > 0; st >>= 1) {
    if (t < st) red[t] = fmaxf(red[t], red[t + st]);
    __syncthreads();
  }
  mx = red[0];
  __syncthreads();
  float e[4];
  float s = 0.f;
#pragma unroll
  for (int i = 0; i < 4; ++i) {
    e[i] = expf(z[i] - mx);
    s += e[i];
  }
  red[t] = s;
  __syncthreads();
  for (int st = 128; st > 0; st >>= 1) {
    if (t < st) red[t] += red[t + st];
    __syncthreads();
  }
  float inv = 1.f / red[0];
#pragma unroll
  for (int i = 0; i < 4; ++i) Wb[(size_t)f * LL + t + i * 256] = f2b(e[i] * inv);
}

// ---------------------------------------------------------------------------
// GEMM-A: Zt[b][o][d] = sum_m w_eff[o,m] * x[b,d,m]     (bf16 out)
//   A = w_eff (bf16, K-contig, global_load_lds)   M = o
//   B = x[b]  (f32,  K-contig, reg-stage + cvt)   N = d, K = m
// 128x128 tile, BK=32, 4 waves (2x2), 16x16x32 bf16 MFMA.
// ---------------------------------------------------------------------------
__global__ __launch_bounds__(256) void gemmA(const unsigned short* __restrict__ weff,
                                             const float* __restrict__ x,
                                             unsigned short* __restrict__ Zt) {
  __shared__ unsigned short Al[128 * 32];
  __shared__ unsigned short Bl[128 * 32];
  const int b = blockIdx.y;
  const int tid = threadIdx.x;
  const int lane = tid & 63;
  const int wave = tid >> 6;
  const int wm = wave >> 1, wn = wave & 1;
  const int tm = blockIdx.x >> 3, tn = blockIdx.x & 7;
  const int lrow = lane & 15, kg = lane >> 4;
  const float* xb = x + (size_t)b * LL * DD;

  f32x4 acc[4][4];
#pragma unroll
  for (int i = 0; i < 4; ++i)
#pragma unroll
    for (int j = 0; j < 4; ++j) acc[i][j] = (f32x4){0.f, 0.f, 0.f, 0.f};

  const int brow = tid >> 2, bcol = (tid & 3) * 8;
  const int arow = lane >> 2, acol = (lane & 3) * 8;

  for (int k0 = 0; k0 < DD; k0 += 32) {
    // A tile via async global->LDS (bf16, 16B/lane, wave-uniform LDS base)
#pragma unroll
    for (int cc = 0; cc < 2; ++cc) {
      int c = 2 * wave + cc;
      const unsigned short* g = weff + (size_t)(tm * 128 + c * 16 + arow) * DD + k0 + acol;
      __builtin_amdgcn_global_load_lds(GPTR(g), LPTR(Al + c * 512), 16, 0, 0);
    }
    // B tile: f32 -> bf16 reg-staged (conflict-free linear ds_write_b128)
#pragma unroll
    for (int ch = 0; ch < 2; ++ch) {
      const float* gp = xb + (size_t)(tn * 128 + ch * 64 + brow) * DD + k0 + bcol;
      float4 v0 = *(const float4*)gp;
      float4 v1 = *(const float4*)(gp + 4);
      uint4 p;
      p.x = (unsigned)f2b(v0.x) | ((unsigned)f2b(v0.y) << 16);
      p.y = (unsigned)f2b(v0.z) | ((unsigned)f2b(v0.w) << 16);
      p.z = (unsigned)f2b(v1.x) | ((unsigned)f2b(v1.y) << 16);
      p.w = (unsigned)f2b(v1.z) | ((unsigned)f2b(v1.w) << 16);
      *(uint4*)&Bl[(ch * 64 + brow) * 32 + bcol] = p;
    }
    __syncthreads();  // drains vmcnt (gload_lds) + lgkm (ds_write)

    bf16x8 af[4], bfr[4];
#pragma unroll
    for (int mi = 0; mi < 4; ++mi)
      af[mi] = __builtin_bit_cast(bf16x8, *(const uint4*)&Al[(wm * 64 + mi * 16 + lrow) * 32 + kg * 8]);
#pragma unroll
    for (int ni = 0; ni < 4; ++ni)
      bfr[ni] = __builtin_bit_cast(bf16x8, *(const uint4*)&Bl[(wn * 64 + ni * 16 + lrow) * 32 + kg * 8]);
#pragma unroll
    for (int mi = 0; mi < 4; ++mi)
#pragma unroll
      for (int ni = 0; ni < 4; ++ni)
        acc[mi][ni] = __builtin_amdgcn_mfma_f32_16x16x32_bf16(af[mi], bfr[ni], acc[mi][ni], 0, 0, 0);
    __syncthreads();
  }

  unsigned short* Zb = Zt + (size_t)b * DD * LL;
#pragma unroll
  for (int mi = 0; mi < 4; ++mi)
#pragma unroll
    for (int ni = 0; ni < 4; ++ni)
#pragma unroll
      for (int j = 0; j < 4; ++j) {
        int r = tm * 128 + wm * 64 + mi * 16 + kg * 4 + j;  // o
        int c = tn * 128 + wn * 64 + ni * 16 + lrow;        // d
        Zb[(size_t)r * LL + c] = f2b(acc[mi][ni][j]);
      }
}

// ---------------------------------------------------------------------------
// GEMM-B: out[b,l,o] = sum_d W[l,d] * Zt[b,o,d] + conv_b[l]*S[o] + out_b[o]
//   A = W  (bf16, K-contig), B = Zt[b] (bf16, K-contig) — both global_load_lds
// ---------------------------------------------------------------------------
__global__ __launch_bounds__(256) void gemmB(const unsigned short* __restrict__ Wm,
                                             const unsigned short* __restrict__ Zt,
                                             const float* __restrict__ conv_b,
                                             const float* __restrict__ S,
                                             const float* __restrict__ out_b,
                                             float* __restrict__ out) {
  __shared__ unsigned short Al[128 * 32];
  __shared__ unsigned short Bl[128 * 32];
  const int b = blockIdx.y;
  const int tid = threadIdx.x;
  const int lane = tid & 63;
  const int wave = tid >> 6;
  const int wm = wave >> 1, wn = wave & 1;
  const int tm = blockIdx.x >> 3, tn = blockIdx.x & 7;
  const int lrow = lane & 15, kg = lane >> 4;
  const unsigned short* Zb = Zt + (size_t)b * DD * LL;

  f32x4 acc[4][4];
#pragma unroll
  for (int i = 0; i < 4; ++i)
#pragma unroll
    for (int j = 0; j < 4; ++j) acc[i][j] = (f32x4){0.f, 0.f, 0.f, 0.f};

  const int arow = lane >> 2, acol = (lane & 3) * 8;

  for (int k0 = 0; k0 < LL; k0 += 32) {
#pragma unroll
    for (int cc = 0; cc < 2; ++cc) {
      int c = 2 * wave + cc;
      const unsigned short* ga = Wm + (size_t)(tm * 128 + c * 16 + arow) * LL + k0 + acol;
      __builtin_amdgcn_global_load_lds(GPTR(ga), LPTR(Al + c * 512), 16, 0, 0);
      const unsigned short* gb = Zb + (size_t)(tn * 128 + c * 16 + arow) * LL + k0 + acol;
      __builtin_amdgcn_global_load_lds(GPTR(gb), LPTR(Bl + c * 512), 16, 0, 0);
    }
    __syncthreads();

    bf16x8 af[4], bfr[4];
#pragma unroll
    for (int mi = 0; mi < 4; ++mi)
      af[mi] = __builtin_bit_cast(bf16x8, *(const uint4*)&Al[(wm * 64 + mi * 16 + lrow) * 32 + kg * 8]);
#pragma unroll
    for (int ni = 0; ni < 4; ++ni)
      bfr[ni] = __builtin_bit_cast(bf16x8, *(const uint4*)&Bl[(wn * 64 + ni * 16 + lrow) * 32 + kg * 8]);
#pragma unroll
    for (int mi = 0; mi < 4; ++mi)
#pragma unroll
      for (int ni = 0; ni < 4; ++ni)
        acc[mi][ni] = __builtin_amdgcn_mfma_f32_16x16x32_bf16(af[mi], bfr[ni], acc[mi][ni], 0, 0, 0);
    __syncthreads();
  }

#pragma unroll
  for (int ni = 0; ni < 4; ++ni) {
    int c = tn * 128 + wn * 64 + ni * 16 + lrow;  // o
    float sc = S[c];
    float ob = out_b[c];
#pragma unroll
    for (int mi = 0; mi < 4; ++mi)
#pragma unroll
      for (int j = 0; j < 4; ++j) {
        int r = tm * 128 + wm * 64 + mi * 16 + kg * 4 + j;  // l
        out[((size_t)b * LL + r) * DD + c] = acc[mi][ni][j] + conv_b[r] * sc + ob;
      }
  }
}

// ---------------------------------------------------------------------------
extern "C" void kernel_launch(void* const* d_in, const int* in_sizes, int n_in,
                              void* d_out, int out_size, void* d_ws, size_t ws_size,
                              hipStream_t stream) {
  const float* x      = (const float*)d_in[0];
  const float* conv_w = (const float*)d_in[1];
  const float* conv_b = (const float*)d_in[2];
  const float* out_w  = (const float*)d_in[3];
  const float* out_b  = (const float*)d_in[4];
  float* out = (float*)d_out;

  char* ws = (char*)d_ws;
  unsigned short* W_bf  = (unsigned short*)ws;                              // 2 MB
  unsigned short* weff  = (unsigned short*)(ws + (2u << 20));               // 2 MB
  float*          S     = (float*)(ws + (4u << 20));                        // 4 KB
  unsigned short* Zt    = (unsigned short*)(ws + (4u << 20) + (1u << 16));  // 32 MB

  hipLaunchKernelGGL(weff_kernel, dim3(DD), dim3(256), 0, stream, out_w, weff, S);
  hipLaunchKernelGGL(softmax_kernel, dim3(LL), dim3(256), 0, stream, conv_w, W_bf);
  hipLaunchKernelGGL(gemmA, dim3(64, NB), dim3(256), 0, stream, weff, x, Zt);
  hipLaunchKernelGGL(gemmB, dim3(64, NB), dim3(256), 0, stream, W_bf, Zt, conv_b, S, out_b, out);
}

// Round 2
// 129.931 us; speedup vs baseline: 1.0639x; 1.0639x over previous
//
#include <hip/hip_runtime.h>
#include <cstdint>

#define LL 1024   // sequence length L
#define DD 1024   // dim D
#define NB 16     // batch
#define NHH 8     // heads

typedef __bf16 bf16x8 __attribute__((ext_vector_type(8)));
typedef float f32x4 __attribute__((ext_vector_type(4)));

#define GPTR(x) ((const __attribute__((address_space(1))) void*)(x))
#define LPTR(x) ((__attribute__((address_space(3))) void*)(x))

static __device__ __forceinline__ unsigned short f2b(float f) {
  unsigned int u = __float_as_uint(f);
  u += 0x7FFFu + ((u >> 16) & 1u);
  return (unsigned short)(u >> 16);
}

// ---------------------------------------------------------------------------
// Kernel 0: x (f32) -> x_bf (bf16), streaming, 8 elem/thread/iter
// ---------------------------------------------------------------------------
__global__ __launch_bounds__(256) void xcvt_kernel(const float* __restrict__ x,
                                                   unsigned short* __restrict__ xb,
                                                   int n8) {
  int i = blockIdx.x * blockDim.x + threadIdx.x;
  const int stride = gridDim.x * blockDim.x;
  for (; i < n8; i += stride) {
    float4 v0 = ((const float4*)x)[2 * i];
    float4 v1 = ((const float4*)x)[2 * i + 1];
    uint4 p;
    p.x = (unsigned)f2b(v0.x) | ((unsigned)f2b(v0.y) << 16);
    p.y = (unsigned)f2b(v0.z) | ((unsigned)f2b(v0.w) << 16);
    p.z = (unsigned)f2b(v1.x) | ((unsigned)f2b(v1.y) << 16);
    p.w = (unsigned)f2b(v1.z) | ((unsigned)f2b(v1.w) << 16);
    ((uint4*)xb)[i] = p;
  }
}

// ---------------------------------------------------------------------------
// Kernel 1: w_eff[o,m] = sum_h out_w[o, h*D + m]  (store bf16), S[o] = sum_m w_eff
// ---------------------------------------------------------------------------
__global__ __launch_bounds__(256) void weff_kernel(const float* __restrict__ out_w,
                                                   unsigned short* __restrict__ weff,
                                                   float* __restrict__ S) {
  const int o = blockIdx.x;
  const int t = threadIdx.x;
  __shared__ float red[256];
  const float* row = out_w + (size_t)o * (DD * NHH);
  float local = 0.f;
#pragma unroll
  for (int i = 0; i < 4; ++i) {
    int m = t + i * 256;
    float s = 0.f;
#pragma unroll
    for (int h = 0; h < NHH; ++h) s += row[h * DD + m];
    weff[(size_t)o * DD + m] = f2b(s);
    local += s;
  }
  red[t] = local;
  __syncthreads();
  for (int st = 128; st > 0; st >>= 1) {
    if (t < st) red[t] += red[t + st];
    __syncthreads();
  }
  if (t == 0) S[o] = red[0];
}

// ---------------------------------------------------------------------------
// Kernel 2: W = softmax(tril(conv_w)) rows; upper triangle contributes exp(0)=1.
// ---------------------------------------------------------------------------
__global__ __launch_bounds__(256) void softmax_kernel(const float* __restrict__ conv_w,
                                                      unsigned short* __restrict__ Wb) {
  const int f = blockIdx.x;
  const int t = threadIdx.x;
  __shared__ float red[256];
  float z[4];
  float mx = -1e30f;
#pragma unroll
  for (int i = 0; i < 4; ++i) {
    int d = t + i * 256;
    float v = conv_w[(size_t)f * LL + d];
    z[i] = (d <= f) ? v : 0.f;
    mx = fmaxf(mx, z[i]);
  }
  red[t] = mx;
  __syncthreads();
  for (int st = 128; st > 0; st >>= 1) {
    if (t < st) red[t] = fmaxf(red[t], red[t + st]);
    __syncthreads();
  }
  mx = red[0];
  __syncthreads();
  float e[4];
  float s = 0.f;
#pragma unroll
  for (int i = 0; i < 4; ++i) {
    e[i] = expf(z[i] - mx);
    s += e[i];
  }
  red[t] = s;
  __syncthreads();
  for (int st = 128; st > 0; st >>= 1) {
    if (t < st) red[t] += red[t + st];
    __syncthreads();
  }
  float inv = 1.f / red[0];
#pragma unroll
  for (int i = 0; i < 4; ++i) Wb[(size_t)f * LL + t + i * 256] = f2b(e[i] * inv);
}

// ---------------------------------------------------------------------------
// GEMM-A (bf16 path): Zt[b][o][d] = sum_m weff[o,m] * x_bf[b,d,m]   (bf16 out)
// Both operands K-contiguous bf16, global_load_lds width=16. m97 structure.
// ---------------------------------------------------------------------------
__global__ __launch_bounds__(256) void gemmA_bf(const unsigned short* __restrict__ weff,
                                                const unsigned short* __restrict__ xb,
                                                unsigned short* __restrict__ Zt) {
  __shared__ unsigned short Al[128 * 32];
  __shared__ unsigned short Bl[128 * 32];
  const int b = blockIdx.y;
  const int tid = threadIdx.x;
  const int lane = tid & 63;
  const int wave = tid >> 6;
  const int wm = wave >> 1, wn = wave & 1;
  const int tm = blockIdx.x >> 3, tn = blockIdx.x & 7;
  const int lrow = lane & 15, kg = lane >> 4;
  const unsigned short* xbb = xb + (size_t)b * LL * DD;

  f32x4 acc[4][4];
#pragma unroll
  for (int i = 0; i < 4; ++i)
#pragma unroll
    for (int j = 0; j < 4; ++j) acc[i][j] = (f32x4){0.f, 0.f, 0.f, 0.f};

  const int arow = lane >> 2, acol = (lane & 3) * 8;

  for (int k0 = 0; k0 < DD; k0 += 32) {
#pragma unroll
    for (int cc = 0; cc < 2; ++cc) {
      int c = 2 * wave + cc;
      const unsigned short* ga = weff + (size_t)(tm * 128 + c * 16 + arow) * DD + k0 + acol;
      __builtin_amdgcn_global_load_lds(GPTR(ga), LPTR(Al + c * 512), 16, 0, 0);
      const unsigned short* gb = xbb + (size_t)(tn * 128 + c * 16 + arow) * DD + k0 + acol;
      __builtin_amdgcn_global_load_lds(GPTR(gb), LPTR(Bl + c * 512), 16, 0, 0);
    }
    __syncthreads();

    bf16x8 af[4], bfr[4];
#pragma unroll
    for (int mi = 0; mi < 4; ++mi)
      af[mi] = __builtin_bit_cast(bf16x8, *(const uint4*)&Al[(wm * 64 + mi * 16 + lrow) * 32 + kg * 8]);
#pragma unroll
    for (int ni = 0; ni < 4; ++ni)
      bfr[ni] = __builtin_bit_cast(bf16x8, *(const uint4*)&Bl[(wn * 64 + ni * 16 + lrow) * 32 + kg * 8]);
#pragma unroll
    for (int mi = 0; mi < 4; ++mi)
#pragma unroll
      for (int ni = 0; ni < 4; ++ni)
        acc[mi][ni] = __builtin_amdgcn_mfma_f32_16x16x32_bf16(af[mi], bfr[ni], acc[mi][ni], 0, 0, 0);
    __syncthreads();
  }

  unsigned short* Zb = Zt + (size_t)b * DD * LL;
#pragma unroll
  for (int mi = 0; mi < 4; ++mi)
#pragma unroll
    for (int ni = 0; ni < 4; ++ni)
#pragma unroll
      for (int j = 0; j < 4; ++j) {
        int r = tm * 128 + wm * 64 + mi * 16 + kg * 4 + j;  // o
        int c = tn * 128 + wn * 64 + ni * 16 + lrow;        // d
        Zb[(size_t)r * LL + c] = f2b(acc[mi][ni][j]);
      }
}

// ---------------------------------------------------------------------------
// GEMM-A fallback (f32 x in-loop convert) — used only if ws too small
// ---------------------------------------------------------------------------
__global__ __launch_bounds__(256) void gemmA_f32(const unsigned short* __restrict__ weff,
                                                 const float* __restrict__ x,
                                                 unsigned short* __restrict__ Zt) {
  __shared__ unsigned short Al[128 * 32];
  __shared__ unsigned short Bl[128 * 32];
  const int b = blockIdx.y;
  const int tid = threadIdx.x;
  const int lane = tid & 63;
  const int wave = tid >> 6;
  const int wm = wave >> 1, wn = wave & 1;
  const int tm = blockIdx.x >> 3, tn = blockIdx.x & 7;
  const int lrow = lane & 15, kg = lane >> 4;
  const float* xbp = x + (size_t)b * LL * DD;

  f32x4 acc[4][4];
#pragma unroll
  for (int i = 0; i < 4; ++i)
#pragma unroll
    for (int j = 0; j < 4; ++j) acc[i][j] = (f32x4){0.f, 0.f, 0.f, 0.f};

  const int brow = tid >> 2, bcol = (tid & 3) * 8;
  const int arow = lane >> 2, acol = (lane & 3) * 8;

  for (int k0 = 0; k0 < DD; k0 += 32) {
#pragma unroll
    for (int cc = 0; cc < 2; ++cc) {
      int c = 2 * wave + cc;
      const unsigned short* g = weff + (size_t)(tm * 128 + c * 16 + arow) * DD + k0 + acol;
      __builtin_amdgcn_global_load_lds(GPTR(g), LPTR(Al + c * 512), 16, 0, 0);
    }
#pragma unroll
    for (int ch = 0; ch < 2; ++ch) {
      const float* gp = xbp + (size_t)(tn * 128 + ch * 64 + brow) * DD + k0 + bcol;
      float4 v0 = *(const float4*)gp;
      float4 v1 = *(const float4*)(gp + 4);
      uint4 p;
      p.x = (unsigned)f2b(v0.x) | ((unsigned)f2b(v0.y) << 16);
      p.y = (unsigned)f2b(v0.z) | ((unsigned)f2b(v0.w) << 16);
      p.z = (unsigned)f2b(v1.x) | ((unsigned)f2b(v1.y) << 16);
      p.w = (unsigned)f2b(v1.z) | ((unsigned)f2b(v1.w) << 16);
      *(uint4*)&Bl[(ch * 64 + brow) * 32 + bcol] = p;
    }
    __syncthreads();

    bf16x8 af[4], bfr[4];
#pragma unroll
    for (int mi = 0; mi < 4; ++mi)
      af[mi] = __builtin_bit_cast(bf16x8, *(const uint4*)&Al[(wm * 64 + mi * 16 + lrow) * 32 + kg * 8]);
#pragma unroll
    for (int ni = 0; ni < 4; ++ni)
      bfr[ni] = __builtin_bit_cast(bf16x8, *(const uint4*)&Bl[(wn * 64 + ni * 16 + lrow) * 32 + kg * 8]);
#pragma unroll
    for (int mi = 0; mi < 4; ++mi)
#pragma unroll
      for (int ni = 0; ni < 4; ++ni)
        acc[mi][ni] = __builtin_amdgcn_mfma_f32_16x16x32_bf16(af[mi], bfr[ni], acc[mi][ni], 0, 0, 0);
    __syncthreads();
  }

  unsigned short* Zb = Zt + (size_t)b * DD * LL;
#pragma unroll
  for (int mi = 0; mi < 4; ++mi)
#pragma unroll
    for (int ni = 0; ni < 4; ++ni)
#pragma unroll
      for (int j = 0; j < 4; ++j) {
        int r = tm * 128 + wm * 64 + mi * 16 + kg * 4 + j;
        int c = tn * 128 + wn * 64 + ni * 16 + lrow;
        Zb[(size_t)r * LL + c] = f2b(acc[mi][ni][j]);
      }
}

// ---------------------------------------------------------------------------
// GEMM-B: out[b,l,o] = sum_d W[l,d] * Zt[b,o,d] + conv_b[l]*S[o] + out_b[o]
// ---------------------------------------------------------------------------
__global__ __launch_bounds__(256) void gemmB(const unsigned short* __restrict__ Wm,
                                             const unsigned short* __restrict__ Zt,
                                             const float* __restrict__ conv_b,
                                             const float* __restrict__ S,
                                             const float* __restrict__ out_b,
                                             float* __restrict__ out) {
  __shared__ unsigned short Al[128 * 32];
  __shared__ unsigned short Bl[128 * 32];
  const int b = blockIdx.y;
  const int tid = threadIdx.x;
  const int lane = tid & 63;
  const int wave = tid >> 6;
  const int wm = wave >> 1, wn = wave & 1;
  const int tm = blockIdx.x >> 3, tn = blockIdx.x & 7;
  const int lrow = lane & 15, kg = lane >> 4;
  const unsigned short* Zb = Zt + (size_t)b * DD * LL;

  f32x4 acc[4][4];
#pragma unroll
  for (int i = 0; i < 4; ++i)
#pragma unroll
    for (int j = 0; j < 4; ++j) acc[i][j] = (f32x4){0.f, 0.f, 0.f, 0.f};

  const int arow = lane >> 2, acol = (lane & 3) * 8;

  for (int k0 = 0; k0 < LL; k0 += 32) {
#pragma unroll
    for (int cc = 0; cc < 2; ++cc) {
      int c = 2 * wave + cc;
      const unsigned short* ga = Wm + (size_t)(tm * 128 + c * 16 + arow) * LL + k0 + acol;
      __builtin_amdgcn_global_load_lds(GPTR(ga), LPTR(Al + c * 512), 16, 0, 0);
      const unsigned short* gb = Zb + (size_t)(tn * 128 + c * 16 + arow) * LL + k0 + acol;
      __builtin_amdgcn_global_load_lds(GPTR(gb), LPTR(Bl + c * 512), 16, 0, 0);
    }
    __syncthreads();

    bf16x8 af[4], bfr[4];
#pragma unroll
    for (int mi = 0; mi < 4; ++mi)
      af[mi] = __builtin_bit_cast(bf16x8, *(const uint4*)&Al[(wm * 64 + mi * 16 + lrow) * 32 + kg * 8]);
#pragma unroll
    for (int ni = 0; ni < 4; ++ni)
      bfr[ni] = __builtin_bit_cast(bf16x8, *(const uint4*)&Bl[(wn * 64 + ni * 16 + lrow) * 32 + kg * 8]);
#pragma unroll
    for (int mi = 0; mi < 4; ++mi)
#pragma unroll
      for (int ni = 0; ni < 4; ++ni)
        acc[mi][ni] = __builtin_amdgcn_mfma_f32_16x16x32_bf16(af[mi], bfr[ni], acc[mi][ni], 0, 0, 0);
    __syncthreads();
  }

#pragma unroll
  for (int ni = 0; ni < 4; ++ni) {
    int c = tn * 128 + wn * 64 + ni * 16 + lrow;  // o
    float sc = S[c];
    float ob = out_b[c];
#pragma unroll
    for (int mi = 0; mi < 4; ++mi)
#pragma unroll
      for (int j = 0; j < 4; ++j) {
        int r = tm * 128 + wm * 64 + mi * 16 + kg * 4 + j;  // l
        out[((size_t)b * LL + r) * DD + c] = acc[mi][ni][j] + conv_b[r] * sc + ob;
      }
  }
}

// ---------------------------------------------------------------------------
extern "C" void kernel_launch(void* const* d_in, const int* in_sizes, int n_in,
                              void* d_out, int out_size, void* d_ws, size_t ws_size,
                              hipStream_t stream) {
  const float* x      = (const float*)d_in[0];
  const float* conv_w = (const float*)d_in[1];
  const float* conv_b = (const float*)d_in[2];
  const float* out_w  = (const float*)d_in[3];
  const float* out_b  = (const float*)d_in[4];
  float* out = (float*)d_out;

  char* ws = (char*)d_ws;
  unsigned short* W_bf = (unsigned short*)ws;                               // 2 MB
  unsigned short* weff = (unsigned short*)(ws + (2u << 20));                // 2 MB
  float*          S    = (float*)(ws + (4u << 20));                         // 64 KB slot
  unsigned short* Zt   = (unsigned short*)(ws + (4u << 20) + (1u << 16));   // 32 MB
  unsigned short* x_bf = (unsigned short*)(ws + (36u << 20) + (1u << 16));  // 32 MB

  const size_t need = (68ull << 20) + (1u << 16);

  hipLaunchKernelGGL(weff_kernel, dim3(DD), dim3(256), 0, stream, out_w, weff, S);
  hipLaunchKernelGGL(softmax_kernel, dim3(LL), dim3(256), 0, stream, conv_w, W_bf);
  if (ws_size >= need) {
    hipLaunchKernelGGL(xcvt_kernel, dim3(2048), dim3(256), 0, stream, x, x_bf,
                       (NB * LL * DD) / 8);
    hipLaunchKernelGGL(gemmA_bf, dim3(64, NB), dim3(256), 0, stream, weff, x_bf, Zt);
  } else {
    hipLaunchKernelGGL(gemmA_f32, dim3(64, NB), dim3(256), 0, stream, weff, x, Zt);
  }
  hipLaunchKernelGGL(gemmB, dim3(64, NB), dim3(256), 0, stream, W_bf, Zt, conv_b, S, out_b, out);
}

// Round 3
// 109.908 us; speedup vs baseline: 1.2577x; 1.1822x over previous
//
#include <hip/hip_runtime.h>
#include <cstdint>

#define LL 1024
#define DD 1024
#define NB 16
#define NHH 8

typedef __bf16 bf16x8 __attribute__((ext_vector_type(8)));
typedef float f32x4 __attribute__((ext_vector_type(4)));
typedef unsigned short u16;

#define GPTR(x) ((const __attribute__((address_space(1))) void*)(x))
#define LPTR(x) ((__attribute__((address_space(3))) void*)(x))
#define BAR()   __builtin_amdgcn_s_barrier()
#define LGKM0() asm volatile("s_waitcnt lgkmcnt(0)" ::: "memory")
#define VMC(N)  asm volatile("s_waitcnt vmcnt(" #N ")" ::: "memory")

static __device__ __forceinline__ u16 f2b(float f) {
  unsigned int u = __float_as_uint(f);
  u += 0x7FFFu + ((u >> 16) & 1u);
  return (u16)(u >> 16);
}

// ---------------------------------------------------------------------------
// x (f32) -> bf16 streaming convert
// ---------------------------------------------------------------------------
__global__ __launch_bounds__(256) void xcvt_kernel(const float* __restrict__ x,
                                                   u16* __restrict__ xb, int n8) {
  int i = blockIdx.x * blockDim.x + threadIdx.x;
  const int stride = gridDim.x * blockDim.x;
  for (; i < n8; i += stride) {
    float4 v0 = ((const float4*)x)[2 * i];
    float4 v1 = ((const float4*)x)[2 * i + 1];
    uint4 p;
    p.x = (unsigned)f2b(v0.x) | ((unsigned)f2b(v0.y) << 16);
    p.y = (unsigned)f2b(v0.z) | ((unsigned)f2b(v0.w) << 16);
    p.z = (unsigned)f2b(v1.x) | ((unsigned)f2b(v1.y) << 16);
    p.w = (unsigned)f2b(v1.z) | ((unsigned)f2b(v1.w) << 16);
    ((uint4*)xb)[i] = p;
  }
}

// ---------------------------------------------------------------------------
// w_eff[o,m] = sum_h out_w[o, h*D+m] (bf16), S[o] = sum_m w_eff[o,m]
// ---------------------------------------------------------------------------
__global__ __launch_bounds__(256) void weff_kernel(const float* __restrict__ out_w,
                                                   u16* __restrict__ weff,
                                                   float* __restrict__ S) {
  const int o = blockIdx.x;
  const int t = threadIdx.x;
  __shared__ float red[256];
  const float4* row = (const float4*)(out_w + (size_t)o * (DD * NHH));
  float4 s4 = {0.f, 0.f, 0.f, 0.f};
#pragma unroll
  for (int h = 0; h < NHH; ++h) {
    float4 v = row[h * 256 + t];
    s4.x += v.x; s4.y += v.y; s4.z += v.z; s4.w += v.w;
  }
  ushort4 p;
  p.x = f2b(s4.x); p.y = f2b(s4.y); p.z = f2b(s4.z); p.w = f2b(s4.w);
  *(ushort4*)&weff[(size_t)o * DD + t * 4] = p;
  red[t] = s4.x + s4.y + s4.z + s4.w;
  __syncthreads();
  for (int st = 128; st > 0; st >>= 1) {
    if (t < st) red[t] += red[t + st];
    __syncthreads();
  }
  if (t == 0) S[o] = red[0];
}

// ---------------------------------------------------------------------------
// W = softmax(tril(conv_w)); upper-tri zeros contribute exp(0)=1 (faithful)
// ---------------------------------------------------------------------------
__global__ __launch_bounds__(256) void softmax_kernel(const float* __restrict__ conv_w,
                                                      u16* __restrict__ Wb) {
  const int f = blockIdx.x;
  const int t = threadIdx.x;
  __shared__ float red[256];
  float z[4];
  float mx = -1e30f;
#pragma unroll
  for (int i = 0; i < 4; ++i) {
    int d = t + i * 256;
    float v = conv_w[(size_t)f * LL + d];
    z[i] = (d <= f) ? v : 0.f;
    mx = fmaxf(mx, z[i]);
  }
  red[t] = mx;
  __syncthreads();
  for (int st = 128; st > 0; st >>= 1) {
    if (t < st) red[t] = fmaxf(red[t], red[t + st]);
    __syncthreads();
  }
  mx = red[0];
  __syncthreads();
  float e[4], s = 0.f;
#pragma unroll
  for (int i = 0; i < 4; ++i) { e[i] = expf(z[i] - mx); s += e[i]; }
  red[t] = s;
  __syncthreads();
  for (int st = 128; st > 0; st >>= 1) {
    if (t < st) red[t] += red[t + st];
    __syncthreads();
  }
  float inv = 1.f / red[0];
#pragma unroll
  for (int i = 0; i < 4; ++i) Wb[(size_t)f * LL + t + i * 256] = f2b(e[i] * inv);
}

// ---------------------------------------------------------------------------
// 8-phase 256x256 GEMM (T1+T2+T3+T4+T5). C[b] = A @ B[b]^T layout:
//   A [1024 x 1024] bf16 K-contig (shared), B [b][1024 x 1024] bf16 K-contig.
// EPI=0: C bf16 (Zt). EPI=1: C f32 + conv_b[r]*S[c] + out_b[c].
// LDS 128KB dynamic: [A0|B0|A1|B1] tiles of 256x64 bf16, st-swizzled
// (logical slot s at row r stored at physical slot s^(r&7); stage pre-swizzles
// the per-lane GLOBAL source so gload_lds's linear dest lands swizzled).
// vmcnt discipline: 8 loads/tile, 2 tiles in flight, waits only at P4/P8.
// ---------------------------------------------------------------------------
__device__ __forceinline__ void stageTile(const u16* __restrict__ g, u16* l,
                                          int wave, int lane) {
  const int rlo = lane >> 3;             // row offset 0..7 within 8-row stripe
  const int sl = (lane & 7) ^ rlo;       // pre-swizzled source slot
#pragma unroll
  for (int j = 0; j < 4; ++j) {
    const u16* src = g + (size_t)(j * 64 + wave * 8 + rlo) * 1024 + sl * 8;
    __builtin_amdgcn_global_load_lds(GPTR(src), LPTR(l + j * 4096 + wave * 512), 16, 0, 0);
  }
}

__device__ __forceinline__ bf16x8 ldsRead(const u16* l, int row, int slot) {
  int off = row * 64 + (((slot) ^ (row & 7)) << 3);
  return __builtin_bit_cast(bf16x8, *(const uint4*)(l + off));
}

template <int EPI>
__global__ __launch_bounds__(512, 2) void gemm8(const u16* __restrict__ A,
                                                const u16* __restrict__ Bm,
                                                void* __restrict__ Cout,
                                                const float* __restrict__ conv_b,
                                                const float* __restrict__ S,
                                                const float* __restrict__ out_b) {
  extern __shared__ u16 lds[];
  u16* A0 = lds;
  u16* B0 = lds + 16384;
  u16* A1 = lds + 32768;
  u16* B1 = lds + 49152;

  int bid = blockIdx.x;
  bid = (bid & 7) * 32 + (bid >> 3);          // T1: contiguous chunk per XCD
  const int b = bid >> 4;
  const int tm = (bid >> 2) & 3;
  const int tn = bid & 3;

  const int tid = threadIdx.x, lane = tid & 63, wave = tid >> 6;
  const int wm = wave >> 2, wn = wave & 3;    // 2 x 4 waves
  const int lrow = lane & 15, kg = lane >> 4;

  const u16* Ablk = A + (size_t)(tm * 256) * 1024;
  const u16* Bblk = Bm + (size_t)b * (1024 * 1024) + (size_t)(tn * 256) * 1024;

  f32x4 acc[8][4];
#pragma unroll
  for (int i = 0; i < 8; ++i)
#pragma unroll
    for (int j = 0; j < 4; ++j) acc[i][j] = (f32x4){0.f, 0.f, 0.f, 0.f};

  bf16x8 af[8], b0r[4], b1r[4];

  auto readAfr = [&](const u16* Ab, int mh) {
#pragma unroll
    for (int q = 0; q < 4; ++q)
#pragma unroll
      for (int ks = 0; ks < 2; ++ks)
        af[q * 2 + ks] = ldsRead(Ab, wm * 128 + (mh * 4 + q) * 16 + lrow, kg + 4 * ks);
  };
  auto readBfr = [&](const u16* Bb, int nh, bf16x8* dst) {
#pragma unroll
    for (int n = 0; n < 2; ++n)
#pragma unroll
      for (int ks = 0; ks < 2; ++ks)
        dst[n * 2 + ks] = ldsRead(Bb, wn * 64 + (nh * 2 + n) * 16 + lrow, kg + 4 * ks);
  };
  auto mfmaQuad = [&](int mh, int nh, bf16x8* bfr) {
    __builtin_amdgcn_s_setprio(1);
#pragma unroll
    for (int q = 0; q < 4; ++q)
#pragma unroll
      for (int n = 0; n < 2; ++n)
#pragma unroll
        for (int ks = 0; ks < 2; ++ks)
          acc[mh * 4 + q][nh * 2 + n] = __builtin_amdgcn_mfma_f32_16x16x32_bf16(
              af[q * 2 + ks], bfr[n * 2 + ks], acc[mh * 4 + q][nh * 2 + n], 0, 0, 0);
    __builtin_amdgcn_s_setprio(0);
  };

  // prologue: t0 -> buf0, t1 -> buf1; wait t0 (8 loads of t1 stay in flight)
  stageTile(Ablk, A0, wave, lane);
  stageTile(Bblk, B0, wave, lane);
  stageTile(Ablk + 64, A1, wave, lane);
  stageTile(Bblk + 64, B1, wave, lane);
  VMC(8);
  BAR();

  for (int i = 0; i < 7; ++i) {
    const int t2 = 2 * i + 2, t3 = 2 * i + 3;
    // ---- tile 2i from buf0 ----
    readAfr(A0, 0); readBfr(B0, 0, b0r); BAR(); LGKM0(); mfmaQuad(0, 0, b0r); BAR();
    readBfr(B0, 1, b1r);                 BAR(); LGKM0(); mfmaQuad(0, 1, b1r); BAR();
    readAfr(A0, 1);                      BAR(); LGKM0(); mfmaQuad(1, 1, b1r); BAR();
    stageTile(Ablk + t2 * 64, A0, wave, lane);   // buf0 fully consumed (P3 barrier)
    stageTile(Bblk + t2 * 64, B0, wave, lane);
    mfmaQuad(1, 0, b0r); VMC(8); BAR();          // completes tile 2i+1's loads
    // ---- tile 2i+1 from buf1 ----
    readAfr(A1, 0); readBfr(B1, 0, b0r); BAR(); LGKM0(); mfmaQuad(0, 0, b0r); BAR();
    readBfr(B1, 1, b1r);                 BAR(); LGKM0(); mfmaQuad(0, 1, b1r); BAR();
    readAfr(A1, 1);                      BAR(); LGKM0(); mfmaQuad(1, 1, b1r); BAR();
    stageTile(Ablk + t3 * 64, A1, wave, lane);
    stageTile(Bblk + t3 * 64, B1, wave, lane);
    mfmaQuad(1, 0, b0r); VMC(8); BAR();          // completes tile 2i+2's loads
  }
  // epilogue: tiles 14 (buf0) and 15 (buf1), no staging
  readAfr(A0, 0); readBfr(B0, 0, b0r); BAR(); LGKM0(); mfmaQuad(0, 0, b0r); BAR();
  readBfr(B0, 1, b1r);                 BAR(); LGKM0(); mfmaQuad(0, 1, b1r); BAR();
  readAfr(A0, 1);                      BAR(); LGKM0(); mfmaQuad(1, 1, b1r); BAR();
  mfmaQuad(1, 0, b0r); VMC(0); BAR();
  readAfr(A1, 0); readBfr(B1, 0, b0r); BAR(); LGKM0(); mfmaQuad(0, 0, b0r); BAR();
  readBfr(B1, 1, b1r);                 BAR(); LGKM0(); mfmaQuad(0, 1, b1r); BAR();
  readAfr(A1, 1);                      BAR(); LGKM0(); mfmaQuad(1, 1, b1r); BAR();
  mfmaQuad(1, 0, b0r);

  if constexpr (EPI == 0) {
    u16* C = (u16*)Cout + (size_t)b * (1024 * 1024);
#pragma unroll
    for (int mi = 0; mi < 8; ++mi)
#pragma unroll
      for (int ni = 0; ni < 4; ++ni)
#pragma unroll
        for (int j = 0; j < 4; ++j) {
          int r = tm * 256 + wm * 128 + mi * 16 + kg * 4 + j;
          int c = tn * 256 + wn * 64 + ni * 16 + lrow;
          C[(size_t)r * 1024 + c] = f2b(acc[mi][ni][j]);
        }
  } else {
    float* C = (float*)Cout + (size_t)b * (1024 * 1024);
#pragma unroll
    for (int ni = 0; ni < 4; ++ni) {
      int c = tn * 256 + wn * 64 + ni * 16 + lrow;
      float sc = S[c], ob = out_b[c];
#pragma unroll
      for (int mi = 0; mi < 8; ++mi)
#pragma unroll
        for (int j = 0; j < 4; ++j) {
          int r = tm * 256 + wm * 128 + mi * 16 + kg * 4 + j;
          C[(size_t)r * 1024 + c] = acc[mi][ni][j] + conv_b[r] * sc + ob;
        }
    }
  }
}

// ---------------------------------------------------------------------------
// Fallback 128^2 2-phase kernels (used only if 128KB-LDS attr or ws fails)
// ---------------------------------------------------------------------------
__global__ __launch_bounds__(256) void gemmA_f32(const u16* __restrict__ weff,
                                                 const float* __restrict__ x,
                                                 u16* __restrict__ Zt) {
  __shared__ u16 Al[128 * 32];
  __shared__ u16 Bl[128 * 32];
  const int b = blockIdx.y;
  const int tid = threadIdx.x, lane = tid & 63, wave = tid >> 6;
  const int wm = wave >> 1, wn = wave & 1;
  const int tm = blockIdx.x >> 3, tn = blockIdx.x & 7;
  const int lrow = lane & 15, kg = lane >> 4;
  const float* xbp = x + (size_t)b * LL * DD;
  f32x4 acc[4][4];
#pragma unroll
  for (int i = 0; i < 4; ++i)
#pragma unroll
    for (int j = 0; j < 4; ++j) acc[i][j] = (f32x4){0.f, 0.f, 0.f, 0.f};
  const int brow = tid >> 2, bcol = (tid & 3) * 8;
  const int arow = lane >> 2, acol = (lane & 3) * 8;
  for (int k0 = 0; k0 < DD; k0 += 32) {
#pragma unroll
    for (int cc = 0; cc < 2; ++cc) {
      int c = 2 * wave + cc;
      const u16* g = weff + (size_t)(tm * 128 + c * 16 + arow) * DD + k0 + acol;
      __builtin_amdgcn_global_load_lds(GPTR(g), LPTR(Al + c * 512), 16, 0, 0);
    }
#pragma unroll
    for (int ch = 0; ch < 2; ++ch) {
      const float* gp = xbp + (size_t)(tn * 128 + ch * 64 + brow) * DD + k0 + bcol;
      float4 v0 = *(const float4*)gp;
      float4 v1 = *(const float4*)(gp + 4);
      uint4 p;
      p.x = (unsigned)f2b(v0.x) | ((unsigned)f2b(v0.y) << 16);
      p.y = (unsigned)f2b(v0.z) | ((unsigned)f2b(v0.w) << 16);
      p.z = (unsigned)f2b(v1.x) | ((unsigned)f2b(v1.y) << 16);
      p.w = (unsigned)f2b(v1.z) | ((unsigned)f2b(v1.w) << 16);
      *(uint4*)&Bl[(ch * 64 + brow) * 32 + bcol] = p;
    }
    __syncthreads();
    bf16x8 a2[4], b2[4];
#pragma unroll
    for (int mi = 0; mi < 4; ++mi)
      a2[mi] = __builtin_bit_cast(bf16x8, *(const uint4*)&Al[(wm * 64 + mi * 16 + lrow) * 32 + kg * 8]);
#pragma unroll
    for (int ni = 0; ni < 4; ++ni)
      b2[ni] = __builtin_bit_cast(bf16x8, *(const uint4*)&Bl[(wn * 64 + ni * 16 + lrow) * 32 + kg * 8]);
#pragma unroll
    for (int mi = 0; mi < 4; ++mi)
#pragma unroll
      for (int ni = 0; ni < 4; ++ni)
        acc[mi][ni] = __builtin_amdgcn_mfma_f32_16x16x32_bf16(a2[mi], b2[ni], acc[mi][ni], 0, 0, 0);
    __syncthreads();
  }
  u16* Zb = Zt + (size_t)b * DD * LL;
#pragma unroll
  for (int mi = 0; mi < 4; ++mi)
#pragma unroll
    for (int ni = 0; ni < 4; ++ni)
#pragma unroll
      for (int j = 0; j < 4; ++j) {
        int r = tm * 128 + wm * 64 + mi * 16 + kg * 4 + j;
        int c = tn * 128 + wn * 64 + ni * 16 + lrow;
        Zb[(size_t)r * LL + c] = f2b(acc[mi][ni][j]);
      }
}

__global__ __launch_bounds__(256) void gemmB2(const u16* __restrict__ Wm,
                                              const u16* __restrict__ Zt,
                                              const float* __restrict__ conv_b,
                                              const float* __restrict__ S,
                                              const float* __restrict__ out_b,
                                              float* __restrict__ out) {
  __shared__ u16 Al[128 * 32];
  __shared__ u16 Bl[128 * 32];
  const int b = blockIdx.y;
  const int tid = threadIdx.x, lane = tid & 63, wave = tid >> 6;
  const int wm = wave >> 1, wn = wave & 1;
  const int tm = blockIdx.x >> 3, tn = blockIdx.x & 7;
  const int lrow = lane & 15, kg = lane >> 4;
  const u16* Zb = Zt + (size_t)b * DD * LL;
  f32x4 acc[4][4];
#pragma unroll
  for (int i = 0; i < 4; ++i)
#pragma unroll
    for (int j = 0; j < 4; ++j) acc[i][j] = (f32x4){0.f, 0.f, 0.f, 0.f};
  const int arow = lane >> 2, acol = (lane & 3) * 8;
  for (int k0 = 0; k0 < LL; k0 += 32) {
#pragma unroll
    for (int cc = 0; cc < 2; ++cc) {
      int c = 2 * wave + cc;
      const u16* ga = Wm + (size_t)(tm * 128 + c * 16 + arow) * LL + k0 + acol;
      __builtin_amdgcn_global_load_lds(GPTR(ga), LPTR(Al + c * 512), 16, 0, 0);
      const u16* gb = Zb + (size_t)(tn * 128 + c * 16 + arow) * LL + k0 + acol;
      __builtin_amdgcn_global_load_lds(GPTR(gb), LPTR(Bl + c * 512), 16, 0, 0);
    }
    __syncthreads();
    bf16x8 a2[4], b2[4];
#pragma unroll
    for (int mi = 0; mi < 4; ++mi)
      a2[mi] = __builtin_bit_cast(bf16x8, *(const uint4*)&Al[(wm * 64 + mi * 16 + lrow) * 32 + kg * 8]);
#pragma unroll
    for (int ni = 0; ni < 4; ++ni)
      b2[ni] = __builtin_bit_cast(bf16x8, *(const uint4*)&Bl[(wn * 64 + ni * 16 + lrow) * 32 + kg * 8]);
#pragma unroll
    for (int mi = 0; mi < 4; ++mi)
#pragma unroll
      for (int ni = 0; ni < 4; ++ni)
        acc[mi][ni] = __builtin_amdgcn_mfma_f32_16x16x32_bf16(a2[mi], b2[ni], acc[mi][ni], 0, 0, 0);
    __syncthreads();
  }
#pragma unroll
  for (int ni = 0; ni < 4; ++ni) {
    int c = tn * 128 + wn * 64 + ni * 16 + lrow;
    float sc = S[c], ob = out_b[c];
#pragma unroll
    for (int mi = 0; mi < 4; ++mi)
#pragma unroll
      for (int j = 0; j < 4; ++j) {
        int r = tm * 128 + wm * 64 + mi * 16 + kg * 4 + j;
        out[((size_t)b * LL + r) * DD + c] = acc[mi][ni][j] + conv_b[r] * sc + ob;
      }
  }
}

// ---------------------------------------------------------------------------
extern "C" void kernel_launch(void* const* d_in, const int* in_sizes, int n_in,
                              void* d_out, int out_size, void* d_ws, size_t ws_size,
                              hipStream_t stream) {
  const float* x      = (const float*)d_in[0];
  const float* conv_w = (const float*)d_in[1];
  const float* conv_b = (const float*)d_in[2];
  const float* out_w  = (const float*)d_in[3];
  const float* out_b  = (const float*)d_in[4];
  float* out = (float*)d_out;

  char* ws = (char*)d_ws;
  u16*   W_bf = (u16*)ws;                                // 2 MB
  u16*   weff = (u16*)(ws + (2u << 20));                 // 2 MB
  float* S    = (float*)(ws + (4u << 20));               // 64 KB slot
  u16*   Zt   = (u16*)(ws + (4u << 20) + (1u << 16));    // 32 MB
  u16*   x_bf = (u16*)(ws + (36u << 20) + (1u << 16));   // 32 MB
  const size_t need = (68ull << 20) + (1u << 16);

  hipError_t e0 = hipFuncSetAttribute(reinterpret_cast<const void*>(gemm8<0>),
                                      hipFuncAttributeMaxDynamicSharedMemorySize, 131072);
  hipError_t e1 = hipFuncSetAttribute(reinterpret_cast<const void*>(gemm8<1>),
                                      hipFuncAttributeMaxDynamicSharedMemorySize, 131072);
  const bool use8 = (e0 == hipSuccess) && (e1 == hipSuccess) && (ws_size >= need);

  hipLaunchKernelGGL(weff_kernel, dim3(DD), dim3(256), 0, stream, out_w, weff, S);
  hipLaunchKernelGGL(softmax_kernel, dim3(LL), dim3(256), 0, stream, conv_w, W_bf);

  if (use8) {
    hipLaunchKernelGGL(xcvt_kernel, dim3(2048), dim3(256), 0, stream, x, x_bf,
                       (NB * LL * DD) / 8);
    hipLaunchKernelGGL((gemm8<0>), dim3(256), dim3(512), 131072, stream,
                       weff, x_bf, (void*)Zt, (const float*)nullptr,
                       (const float*)nullptr, (const float*)nullptr);
    hipLaunchKernelGGL((gemm8<1>), dim3(256), dim3(512), 131072, stream,
                       W_bf, Zt, (void*)out, conv_b, S, out_b);
  } else {
    hipLaunchKernelGGL(gemmA_f32, dim3(64, NB), dim3(256), 0, stream, weff, x, Zt);
    hipLaunchKernelGGL(gemmB2, dim3(64, NB), dim3(256), 0, stream, W_bf, Zt, conv_b, S, out_b, out);
  }
}

// Round 4
// 103.774 us; speedup vs baseline: 1.3320x; 1.0591x over previous
//
#include <hip/hip_runtime.h>
#include <cstdint>

#define LL 1024
#define DD 1024
#define NB 16
#define NHH 8

typedef __bf16 bf16x8 __attribute__((ext_vector_type(8)));
typedef float f32x4 __attribute__((ext_vector_type(4)));
typedef unsigned short u16;

#define GPTR(x) ((const __attribute__((address_space(1))) void*)(x))
#define LPTR(x) ((__attribute__((address_space(3))) void*)(x))
#define BAR()   __builtin_amdgcn_s_barrier()
#define LGKM0() asm volatile("s_waitcnt lgkmcnt(0)" ::: "memory")
#define VMC(N)  asm volatile("s_waitcnt vmcnt(" #N ")" ::: "memory")

static __device__ __forceinline__ u16 f2b(float f) {
  unsigned int u = __float_as_uint(f);
  u += 0x7FFFu + ((u >> 16) & 1u);
  return (u16)(u >> 16);
}

// ---------------------------------------------------------------------------
// x (f32) -> bf16 streaming convert
// ---------------------------------------------------------------------------
__global__ __launch_bounds__(256) void xcvt_kernel(const float* __restrict__ x,
                                                   u16* __restrict__ xb, int n8) {
  int i = blockIdx.x * blockDim.x + threadIdx.x;
  const int stride = gridDim.x * blockDim.x;
  for (; i < n8; i += stride) {
    float4 v0 = ((const float4*)x)[2 * i];
    float4 v1 = ((const float4*)x)[2 * i + 1];
    uint4 p;
    p.x = (unsigned)f2b(v0.x) | ((unsigned)f2b(v0.y) << 16);
    p.y = (unsigned)f2b(v0.z) | ((unsigned)f2b(v0.w) << 16);
    p.z = (unsigned)f2b(v1.x) | ((unsigned)f2b(v1.y) << 16);
    p.w = (unsigned)f2b(v1.z) | ((unsigned)f2b(v1.w) << 16);
    ((uint4*)xb)[i] = p;
  }
}

// ---------------------------------------------------------------------------
// w_eff[o,m] = sum_h out_w[o, h*D+m] (bf16), S[o] = sum_m w_eff[o,m]
// ---------------------------------------------------------------------------
__global__ __launch_bounds__(256) void weff_kernel(const float* __restrict__ out_w,
                                                   u16* __restrict__ weff,
                                                   float* __restrict__ S) {
  const int o = blockIdx.x;
  const int t = threadIdx.x;
  __shared__ float red[256];
  const float4* row = (const float4*)(out_w + (size_t)o * (DD * NHH));
  float4 s4 = {0.f, 0.f, 0.f, 0.f};
#pragma unroll
  for (int h = 0; h < NHH; ++h) {
    float4 v = row[h * 256 + t];
    s4.x += v.x; s4.y += v.y; s4.z += v.z; s4.w += v.w;
  }
  ushort4 p;
  p.x = f2b(s4.x); p.y = f2b(s4.y); p.z = f2b(s4.z); p.w = f2b(s4.w);
  *(ushort4*)&weff[(size_t)o * DD + t * 4] = p;
  red[t] = s4.x + s4.y + s4.z + s4.w;
  __syncthreads();
  for (int st = 128; st > 0; st >>= 1) {
    if (t < st) red[t] += red[t + st];
    __syncthreads();
  }
  if (t == 0) S[o] = red[0];
}

// ---------------------------------------------------------------------------
// W = softmax(tril(conv_w)); upper-tri zeros contribute exp(0)=1 (faithful)
// ---------------------------------------------------------------------------
__global__ __launch_bounds__(256) void softmax_kernel(const float* __restrict__ conv_w,
                                                      u16* __restrict__ Wb) {
  const int f = blockIdx.x;
  const int t = threadIdx.x;
  __shared__ float red[256];
  float z[4];
  float mx = -1e30f;
#pragma unroll
  for (int i = 0; i < 4; ++i) {
    int d = t + i * 256;
    float v = conv_w[(size_t)f * LL + d];
    z[i] = (d <= f) ? v : 0.f;
    mx = fmaxf(mx, z[i]);
  }
  red[t] = mx;
  __syncthreads();
  for (int st = 128; st > 0; st >>= 1) {
    if (t < st) red[t] = fmaxf(red[t], red[t + st]);
    __syncthreads();
  }
  mx = red[0];
  __syncthreads();
  float e[4], s = 0.f;
#pragma unroll
  for (int i = 0; i < 4; ++i) { e[i] = expf(z[i] - mx); s += e[i]; }
  red[t] = s;
  __syncthreads();
  for (int st = 128; st > 0; st >>= 1) {
    if (t < st) red[t] += red[t + st];
    __syncthreads();
  }
  float inv = 1.f / red[0];
#pragma unroll
  for (int i = 0; i < 4; ++i) Wb[(size_t)f * LL + t + i * 256] = f2b(e[i] * inv);
}

// ---------------------------------------------------------------------------
// 8-phase 256x256 GEMM (T1+T2+T3+T4+T5), LDS-staged coalesced epilogue.
//   A [1024x1024] bf16 K-contig (shared), B [b][1024x1024] bf16 K-contig.
// EPI=0: C bf16 (Zt). EPI=1: C f32 + conv_b[r]*S[c] + out_b[c].
// ---------------------------------------------------------------------------
__device__ __forceinline__ void stageTile(const u16* __restrict__ g, u16* l,
                                          int wave, int lane) {
  const int rlo = lane >> 3;
  const int sl = (lane & 7) ^ rlo;       // pre-swizzled source slot
#pragma unroll
  for (int j = 0; j < 4; ++j) {
    const u16* src = g + (size_t)(j * 64 + wave * 8 + rlo) * 1024 + sl * 8;
    __builtin_amdgcn_global_load_lds(GPTR(src), LPTR(l + j * 4096 + wave * 512), 16, 0, 0);
  }
}

__device__ __forceinline__ bf16x8 ldsRead(const u16* l, int row, int slot) {
  int off = row * 64 + (((slot) ^ (row & 7)) << 3);
  return __builtin_bit_cast(bf16x8, *(const uint4*)(l + off));
}

template <int EPI>
__global__ __launch_bounds__(512, 2) void gemm8(const u16* __restrict__ A,
                                                const u16* __restrict__ Bm,
                                                void* __restrict__ Cout,
                                                const float* __restrict__ conv_b,
                                                const float* __restrict__ S,
                                                const float* __restrict__ out_b) {
  extern __shared__ u16 lds[];
  u16* A0 = lds;
  u16* B0 = lds + 16384;
  u16* A1 = lds + 32768;
  u16* B1 = lds + 49152;

  int bid = blockIdx.x;
  bid = (bid & 7) * 32 + (bid >> 3);          // T1: contiguous chunk per XCD
  const int b = bid >> 4;
  const int tm = (bid >> 2) & 3;
  const int tn = bid & 3;

  const int tid = threadIdx.x, lane = tid & 63, wave = tid >> 6;
  const int wm = wave >> 2, wn = wave & 3;    // 2 x 4 waves
  const int lrow = lane & 15, kg = lane >> 4;

  const u16* Ablk = A + (size_t)(tm * 256) * 1024;
  const u16* Bblk = Bm + (size_t)b * (1024 * 1024) + (size_t)(tn * 256) * 1024;

  f32x4 acc[8][4];
#pragma unroll
  for (int i = 0; i < 8; ++i)
#pragma unroll
    for (int j = 0; j < 4; ++j) acc[i][j] = (f32x4){0.f, 0.f, 0.f, 0.f};

  bf16x8 af[8], b0r[4], b1r[4];

  auto readAfr = [&](const u16* Ab, int mh) {
#pragma unroll
    for (int q = 0; q < 4; ++q)
#pragma unroll
      for (int ks = 0; ks < 2; ++ks)
        af[q * 2 + ks] = ldsRead(Ab, wm * 128 + (mh * 4 + q) * 16 + lrow, kg + 4 * ks);
  };
  auto readBfr = [&](const u16* Bb, int nh, bf16x8* dst) {
#pragma unroll
    for (int n = 0; n < 2; ++n)
#pragma unroll
      for (int ks = 0; ks < 2; ++ks)
        dst[n * 2 + ks] = ldsRead(Bb, wn * 64 + (nh * 2 + n) * 16 + lrow, kg + 4 * ks);
  };
  auto mfmaQuad = [&](int mh, int nh, bf16x8* bfr) {
    __builtin_amdgcn_s_setprio(1);
#pragma unroll
    for (int q = 0; q < 4; ++q)
#pragma unroll
      for (int n = 0; n < 2; ++n)
#pragma unroll
        for (int ks = 0; ks < 2; ++ks)
          acc[mh * 4 + q][nh * 2 + n] = __builtin_amdgcn_mfma_f32_16x16x32_bf16(
              af[q * 2 + ks], bfr[n * 2 + ks], acc[mh * 4 + q][nh * 2 + n], 0, 0, 0);
    __builtin_amdgcn_s_setprio(0);
  };

  // prologue: t0 -> buf0, t1 -> buf1; wait t0 (8 loads of t1 stay in flight)
  stageTile(Ablk, A0, wave, lane);
  stageTile(Bblk, B0, wave, lane);
  stageTile(Ablk + 64, A1, wave, lane);
  stageTile(Bblk + 64, B1, wave, lane);
  VMC(8);
  BAR();

  for (int i = 0; i < 7; ++i) {
    const int t2 = 2 * i + 2, t3 = 2 * i + 3;
    // ---- tile 2i from buf0 ----
    readAfr(A0, 0); readBfr(B0, 0, b0r); BAR(); LGKM0(); mfmaQuad(0, 0, b0r); BAR();
    readBfr(B0, 1, b1r);                 BAR(); LGKM0(); mfmaQuad(0, 1, b1r); BAR();
    readAfr(A0, 1);                      BAR(); LGKM0(); mfmaQuad(1, 1, b1r); BAR();
    stageTile(Ablk + t2 * 64, A0, wave, lane);   // buf0 fully consumed (P3 barrier)
    stageTile(Bblk + t2 * 64, B0, wave, lane);
    mfmaQuad(1, 0, b0r); VMC(8); BAR();          // completes tile 2i+1's loads
    // ---- tile 2i+1 from buf1 ----
    readAfr(A1, 0); readBfr(B1, 0, b0r); BAR(); LGKM0(); mfmaQuad(0, 0, b0r); BAR();
    readBfr(B1, 1, b1r);                 BAR(); LGKM0(); mfmaQuad(0, 1, b1r); BAR();
    readAfr(A1, 1);                      BAR(); LGKM0(); mfmaQuad(1, 1, b1r); BAR();
    stageTile(Ablk + t3 * 64, A1, wave, lane);
    stageTile(Bblk + t3 * 64, B1, wave, lane);
    mfmaQuad(1, 0, b0r); VMC(8); BAR();          // completes tile 2i+2's loads
  }
  // epilogue tiles: 14 (buf0) and 15 (buf1), no staging
  readAfr(A0, 0); readBfr(B0, 0, b0r); BAR(); LGKM0(); mfmaQuad(0, 0, b0r); BAR();
  readBfr(B0, 1, b1r);                 BAR(); LGKM0(); mfmaQuad(0, 1, b1r); BAR();
  readAfr(A0, 1);                      BAR(); LGKM0(); mfmaQuad(1, 1, b1r); BAR();
  mfmaQuad(1, 0, b0r); VMC(0); BAR();
  readAfr(A1, 0); readBfr(B1, 0, b0r); BAR(); LGKM0(); mfmaQuad(0, 0, b0r); BAR();
  readBfr(B1, 1, b1r);                 BAR(); LGKM0(); mfmaQuad(0, 1, b1r); BAR();
  readAfr(A1, 1);                      BAR(); LGKM0(); mfmaQuad(1, 1, b1r); BAR();
  mfmaQuad(1, 0, b0r);

  // all waves' ds_reads are complete before this barrier (each wave LGKM0'd
  // before its final MFMAs) -> safe to reuse the LDS for the epilogue.
  BAR();

  if constexpr (EPI == 0) {
    // acc -> LDS (256x256 bf16 = 128 KiB, bank-swizzled), then coalesced store
    u16* E = lds;
#pragma unroll
    for (int mi = 0; mi < 8; ++mi)
#pragma unroll
      for (int ni = 0; ni < 4; ++ni)
#pragma unroll
        for (int j = 0; j < 4; ++j) {
          int r = wm * 128 + mi * 16 + kg * 4 + j;
          int c = wn * 64 + ni * 16 + lrow;
          E[r * 256 + (c ^ (((r >> 2) & 3) << 4))] = f2b(acc[mi][ni][j]);
        }
    __syncthreads();
    u16* Cb = (u16*)Cout + (size_t)b * (1024 * 1024) + (size_t)(tm * 256) * 1024 + tn * 256;
#pragma unroll
    for (int i = 0; i < 16; ++i) {
      int r = i * 16 + (tid >> 5);
      int cl = (tid & 31) * 8;
      uint4 v = *(const uint4*)&E[r * 256 + (cl ^ (((r >> 2) & 3) << 4))];
      *(uint4*)&Cb[(size_t)r * 1024 + cl] = v;
    }
  } else {
    // two 128-row halves through LDS (128 KiB f32 each), bias fused at write
    float* Ef = (float*)lds;
    float* Cf = (float*)Cout + (size_t)b * (1024 * 1024) + (size_t)(tm * 256) * 1024 + tn * 256;
#pragma unroll
    for (int h = 0; h < 2; ++h) {
      if (h) __syncthreads();  // half-0 readers done before overwrite
#pragma unroll
      for (int mi2 = 0; mi2 < 4; ++mi2) {
        int mi = 4 * h + mi2;
#pragma unroll
        for (int ni = 0; ni < 4; ++ni) {
          int c = wn * 64 + ni * 16 + lrow;
          float sc = S[tn * 256 + c], ob = out_b[tn * 256 + c];
#pragma unroll
          for (int j = 0; j < 4; ++j) {
            int li = wm * 64 + mi2 * 16 + kg * 4 + j;
            int rg = tm * 256 + wm * 128 + mi * 16 + kg * 4 + j;
            Ef[li * 256 + (c ^ ((li & 4) << 2))] = acc[mi][ni][j] + conv_b[rg] * sc + ob;
          }
        }
      }
      __syncthreads();
#pragma unroll
      for (int i = 0; i < 16; ++i) {
        int li = i * 8 + (tid >> 6);
        int cl = (tid & 63) * 4;
        float4 v = *(const float4*)&Ef[li * 256 + (cl ^ ((li & 4) << 2))];
        int rblk = (li >> 6) * 128 + h * 64 + (li & 63);
        *(float4*)&Cf[(size_t)rblk * 1024 + cl] = v;
      }
    }
  }
}

// ---------------------------------------------------------------------------
// Fallback 128^2 2-phase kernels (used only if 128KB-LDS attr or ws fails)
// ---------------------------------------------------------------------------
__global__ __launch_bounds__(256) void gemmA_f32(const u16* __restrict__ weff,
                                                 const float* __restrict__ x,
                                                 u16* __restrict__ Zt) {
  __shared__ u16 Al[128 * 32];
  __shared__ u16 Bl[128 * 32];
  const int b = blockIdx.y;
  const int tid = threadIdx.x, lane = tid & 63, wave = tid >> 6;
  const int wm = wave >> 1, wn = wave & 1;
  const int tm = blockIdx.x >> 3, tn = blockIdx.x & 7;
  const int lrow = lane & 15, kg = lane >> 4;
  const float* xbp = x + (size_t)b * LL * DD;
  f32x4 acc[4][4];
#pragma unroll
  for (int i = 0; i < 4; ++i)
#pragma unroll
    for (int j = 0; j < 4; ++j) acc[i][j] = (f32x4){0.f, 0.f, 0.f, 0.f};
  const int brow = tid >> 2, bcol = (tid & 3) * 8;
  const int arow = lane >> 2, acol = (lane & 3) * 8;
  for (int k0 = 0; k0 < DD; k0 += 32) {
#pragma unroll
    for (int cc = 0; cc < 2; ++cc) {
      int c = 2 * wave + cc;
      const u16* g = weff + (size_t)(tm * 128 + c * 16 + arow) * DD + k0 + acol;
      __builtin_amdgcn_global_load_lds(GPTR(g), LPTR(Al + c * 512), 16, 0, 0);
    }
#pragma unroll
    for (int ch = 0; ch < 2; ++ch) {
      const float* gp = xbp + (size_t)(tn * 128 + ch * 64 + brow) * DD + k0 + bcol;
      float4 v0 = *(const float4*)gp;
      float4 v1 = *(const float4*)(gp + 4);
      uint4 p;
      p.x = (unsigned)f2b(v0.x) | ((unsigned)f2b(v0.y) << 16);
      p.y = (unsigned)f2b(v0.z) | ((unsigned)f2b(v0.w) << 16);
      p.z = (unsigned)f2b(v1.x) | ((unsigned)f2b(v1.y) << 16);
      p.w = (unsigned)f2b(v1.z) | ((unsigned)f2b(v1.w) << 16);
      *(uint4*)&Bl[(ch * 64 + brow) * 32 + bcol] = p;
    }
    __syncthreads();
    bf16x8 a2[4], b2[4];
#pragma unroll
    for (int mi = 0; mi < 4; ++mi)
      a2[mi] = __builtin_bit_cast(bf16x8, *(const uint4*)&Al[(wm * 64 + mi * 16 + lrow) * 32 + kg * 8]);
#pragma unroll
    for (int ni = 0; ni < 4; ++ni)
      b2[ni] = __builtin_bit_cast(bf16x8, *(const uint4*)&Bl[(wn * 64 + ni * 16 + lrow) * 32 + kg * 8]);
#pragma unroll
    for (int mi = 0; mi < 4; ++mi)
#pragma unroll
      for (int ni = 0; ni < 4; ++ni)
        acc[mi][ni] = __builtin_amdgcn_mfma_f32_16x16x32_bf16(a2[mi], b2[ni], acc[mi][ni], 0, 0, 0);
    __syncthreads();
  }
  u16* Zb = Zt + (size_t)b * DD * LL;
#pragma unroll
  for (int mi = 0; mi < 4; ++mi)
#pragma unroll
    for (int ni = 0; ni < 4; ++ni)
#pragma unroll
      for (int j = 0; j < 4; ++j) {
        int r = tm * 128 + wm * 64 + mi * 16 + kg * 4 + j;
        int c = tn * 128 + wn * 64 + ni * 16 + lrow;
        Zb[(size_t)r * LL + c] = f2b(acc[mi][ni][j]);
      }
}

__global__ __launch_bounds__(256) void gemmB2(const u16* __restrict__ Wm,
                                              const u16* __restrict__ Zt,
                                              const float* __restrict__ conv_b,
                                              const float* __restrict__ S,
                                              const float* __restrict__ out_b,
                                              float* __restrict__ out) {
  __shared__ u16 Al[128 * 32];
  __shared__ u16 Bl[128 * 32];
  const int b = blockIdx.y;
  const int tid = threadIdx.x, lane = tid & 63, wave = tid >> 6;
  const int wm = wave >> 1, wn = wave & 1;
  const int tm = blockIdx.x >> 3, tn = blockIdx.x & 7;
  const int lrow = lane & 15, kg = lane >> 4;
  const u16* Zb = Zt + (size_t)b * DD * LL;
  f32x4 acc[4][4];
#pragma unroll
  for (int i = 0; i < 4; ++i)
#pragma unroll
    for (int j = 0; j < 4; ++j) acc[i][j] = (f32x4){0.f, 0.f, 0.f, 0.f};
  const int arow = lane >> 2, acol = (lane & 3) * 8;
  for (int k0 = 0; k0 < LL; k0 += 32) {
#pragma unroll
    for (int cc = 0; cc < 2; ++cc) {
      int c = 2 * wave + cc;
      const u16* ga = Wm + (size_t)(tm * 128 + c * 16 + arow) * LL + k0 + acol;
      __builtin_amdgcn_global_load_lds(GPTR(ga), LPTR(Al + c * 512), 16, 0, 0);
      const u16* gb = Zb + (size_t)(tn * 128 + c * 16 + arow) * LL + k0 + acol;
      __builtin_amdgcn_global_load_lds(GPTR(gb), LPTR(Bl + c * 512), 16, 0, 0);
    }
    __syncthreads();
    bf16x8 a2[4], b2[4];
#pragma unroll
    for (int mi = 0; mi < 4; ++mi)
      a2[mi] = __builtin_bit_cast(bf16x8, *(const uint4*)&Al[(wm * 64 + mi * 16 + lrow) * 32 + kg * 8]);
#pragma unroll
    for (int ni = 0; ni < 4; ++ni)
      b2[ni] = __builtin_bit_cast(bf16x8, *(const uint4*)&Bl[(wn * 64 + ni * 16 + lrow) * 32 + kg * 8]);
#pragma unroll
    for (int mi = 0; mi < 4; ++mi)
#pragma unroll
      for (int ni = 0; ni < 4; ++ni)
        acc[mi][ni] = __builtin_amdgcn_mfma_f32_16x16x32_bf16(a2[mi], b2[ni], acc[mi][ni], 0, 0, 0);
    __syncthreads();
  }
#pragma unroll
  for (int ni = 0; ni < 4; ++ni) {
    int c = tn * 128 + wn * 64 + ni * 16 + lrow;
    float sc = S[c], ob = out_b[c];
#pragma unroll
    for (int mi = 0; mi < 4; ++mi)
#pragma unroll
      for (int j = 0; j < 4; ++j) {
        int r = tm * 128 + wm * 64 + mi * 16 + kg * 4 + j;
        out[((size_t)b * LL + r) * DD + c] = acc[mi][ni][j] + conv_b[r] * sc + ob;
      }
  }
}

// ---------------------------------------------------------------------------
extern "C" void kernel_launch(void* const* d_in, const int* in_sizes, int n_in,
                              void* d_out, int out_size, void* d_ws, size_t ws_size,
                              hipStream_t stream) {
  const float* x      = (const float*)d_in[0];
  const float* conv_w = (const float*)d_in[1];
  const float* conv_b = (const float*)d_in[2];
  const float* out_w  = (const float*)d_in[3];
  const float* out_b  = (const float*)d_in[4];
  float* out = (float*)d_out;

  char* ws = (char*)d_ws;
  u16*   W_bf = (u16*)ws;                                // 2 MB
  u16*   weff = (u16*)(ws + (2u << 20));                 // 2 MB
  float* S    = (float*)(ws + (4u << 20));               // 64 KB slot
  u16*   Zt   = (u16*)(ws + (4u << 20) + (1u << 16));    // 32 MB
  u16*   x_bf = (u16*)(ws + (36u << 20) + (1u << 16));   // 32 MB
  const size_t need = (68ull << 20) + (1u << 16);

  hipError_t e0 = hipFuncSetAttribute(reinterpret_cast<const void*>(gemm8<0>),
                                      hipFuncAttributeMaxDynamicSharedMemorySize, 131072);
  hipError_t e1 = hipFuncSetAttribute(reinterpret_cast<const void*>(gemm8<1>),
                                      hipFuncAttributeMaxDynamicSharedMemorySize, 131072);
  const bool use8 = (e0 == hipSuccess) && (e1 == hipSuccess) && (ws_size >= need);

  hipLaunchKernelGGL(weff_kernel, dim3(DD), dim3(256), 0, stream, out_w, weff, S);
  hipLaunchKernelGGL(softmax_kernel, dim3(LL), dim3(256), 0, stream, conv_w, W_bf);

  if (use8) {
    hipLaunchKernelGGL(xcvt_kernel, dim3(2048), dim3(256), 0, stream, x, x_bf,
                       (NB * LL * DD) / 8);
    hipLaunchKernelGGL((gemm8<0>), dim3(256), dim3(512), 131072, stream,
                       weff, x_bf, (void*)Zt, (const float*)nullptr,
                       (const float*)nullptr, (const float*)nullptr);
    hipLaunchKernelGGL((gemm8<1>), dim3(256), dim3(512), 131072, stream,
                       W_bf, Zt, (void*)out, conv_b, S, out_b);
  } else {
    hipLaunchKernelGGL(gemmA_f32, dim3(64, NB), dim3(256), 0, stream, weff, x, Zt);
    hipLaunchKernelGGL(gemmB2, dim3(64, NB), dim3(256), 0, stream, W_bf, Zt, conv_b, S, out_b, out);
  }
}